// Round 2
// baseline (126.152 us; speedup 1.0000x reference)
//
#include <hip/hip_runtime.h>
#include <math.h>

// Problem constants (from reference): B=4, N=8, T=4096, D=1024, TEMPERATURE=1
#define BB 4
#define NN 8
#define TT 4096
#define DD 1024

// One block per (b,t). 256 threads, each owns 4 consecutive d-elements (float4).
// Reads e exactly once (512 MB), writes e_out (64 MB) + tiny aux outputs.
//
// Correctness-critical: argmax must be taken over the f32-QUANTIZED sigmoid
// values (first-index tie-break), not over raw dots — sigmoid saturates to
// exactly 1.0f for dot >~ 16.7 (common here since dot ~ N(0,32)), and the
// reference (jnp/np.argmax over f32 sigmoid) picks the FIRST tied concept.
__global__ __launch_bounds__(256) void gate_kernel(
    const float* __restrict__ e,       // [B,N,T,D]
    const float* __restrict__ w,       // [N,D] (trailing dim 1 squeezed)
    float* __restrict__ e_out,         // [B,T,D]
    float* __restrict__ one_hot,       // [B,N,T] (values 0.0/1.0)
    float* __restrict__ smax,          // [B,T]
    float* __restrict__ sind)          // [B,T] (values 0..7 as float)
{
    const int bt   = blockIdx.x;       // 0 .. B*T-1
    const int b    = bt / TT;
    const int t    = bt - b * TT;
    const int tid  = threadIdx.x;      // 0..255
    const int lane = tid & 63;
    const int wv   = tid >> 6;         // wave id 0..3
    const int d0   = tid * 4;

    // Per-thread: load w-fragment + e-fragment for all 8 concepts, keep e frags.
    float4 frag[NN];
    float  dot[NN];
#pragma unroll
    for (int n = 0; n < NN; ++n) {
        const float4 wf = *reinterpret_cast<const float4*>(&w[(size_t)n * DD + d0]);
        const float4 ef = *reinterpret_cast<const float4*>(
            &e[(((size_t)b * NN + n) * TT + t) * DD + d0]);
        frag[n] = ef;
        dot[n]  = ef.x * wf.x + ef.y * wf.y + ef.z * wf.z + ef.w * wf.w;
    }

    // Wave-level tree reduction (64 lanes) of all 8 dots.
#pragma unroll
    for (int off = 32; off > 0; off >>= 1) {
#pragma unroll
        for (int n = 0; n < NN; ++n)
            dot[n] += __shfl_down(dot[n], off, 64);
    }

    __shared__ float partial[4][NN];
    __shared__ float s_scale;
    __shared__ int   s_win;
    if (lane == 0) {
#pragma unroll
        for (int n = 0; n < NN; ++n) partial[wv][n] = dot[n];
    }
    __syncthreads();

    if (tid == 0) {
        float best = -1.0f;   // sigmoid in (0,1), any real dot beats this
        int   bi   = 0;
#pragma unroll
        for (int n = 0; n < NN; ++n) {
            const float dn = partial[0][n] + partial[1][n] + partial[2][n] + partial[3][n];
            const float sn = 1.0f / (1.0f + expf(-dn));   // f32-quantized sigmoid
            if (sn > best) { best = sn; bi = n; }          // strict > = first-max tie-break
        }
        s_scale = best;
        s_win   = bi;
        smax[bt] = best;          // scale_max_val (the quantized sigmoid max)
        sind[bt] = (float)bi;     // scale_max_ind (read back as float values)
    }
    __syncthreads();

    const int   win = s_win;
    const float sc  = s_scale;

    // one_hot[b, n, t] — 8 scattered 4B writes per block (tiny volume).
    if (tid < NN) {
        one_hot[((size_t)b * NN + tid) * TT + t] = (tid == win) ? 1.0f : 0.0f;
    }

    // Select winner fragment with compile-time indices (no scratch spill).
    float4 o = frag[0];
#pragma unroll
    for (int n = 1; n < NN; ++n) {
        if (n == win) o = frag[n];
    }
    o.x *= sc; o.y *= sc; o.z *= sc; o.w *= sc;
    *reinterpret_cast<float4*>(&e_out[((size_t)b * TT + t) * DD + d0]) = o;
}

extern "C" void kernel_launch(void* const* d_in, const int* in_sizes, int n_in,
                              void* d_out, int out_size, void* d_ws, size_t ws_size,
                              hipStream_t stream) {
    const float* e = (const float*)d_in[0];   // [B,N,T,D] fp32
    const float* w = (const float*)d_in[1];   // [N,D,1]  fp32

    float* out     = (float*)d_out;
    float* e_out   = out;                                          // B*T*D = 16777216
    float* one_hot = e_out + (size_t)BB * TT * DD;                 // B*N*T = 131072
    float* smax    = one_hot + (size_t)BB * NN * TT;               // B*T   = 16384
    float* sind    = smax + (size_t)BB * TT;                       // B*T   = 16384

    gate_kernel<<<BB * TT, 256, 0, stream>>>(e, w, e_out, one_hot, smax, sind);
}

// Round 3
// 122.561 us; speedup vs baseline: 1.0293x; 1.0293x over previous
//
#include <hip/hip_runtime.h>
#include <math.h>

// Problem constants (from reference): B=4, N=8, T=4096, D=1024, TEMPERATURE=1
#define BB 4
#define NN 8
#define TT 4096
#define DD 1024

// Wave-autonomous: one 64-lane wave per (b,t). No LDS, no __syncthreads.
// 4 waves per 256-thread block, each fully independent.
//
// Per (b,t): each lane accumulates partial dots for all 8 concepts over
// 4 coalesced float4 rounds (lane*16B contiguous per round), then a full
// xor-butterfly gives every lane all 8 dot totals. Every lane redundantly
// computes the f32-quantized sigmoid + first-max argmax (bitwise-identical
// across lanes -> no divergence, no broadcast needed). Winner row is
// re-read (cache-hot) and scaled into e_out.
//
// Correctness-critical: argmax over the f32-QUANTIZED sigmoid (strict >,
// first-index tie-break) — sigmoid saturates to exactly 1.0f for dot >~16.7,
// which is common here (dot ~ N(0,32)); jnp.argmax picks the FIRST tie.
__global__ __launch_bounds__(256) void gate_kernel(
    const float* __restrict__ e,       // [B,N,T,D]
    const float* __restrict__ w,       // [N,D]
    float* __restrict__ e_out,         // [B,T,D]
    float* __restrict__ one_hot,       // [B,N,T] (0.0/1.0)
    float* __restrict__ smax,          // [B,T]
    float* __restrict__ sind)          // [B,T] (0..7 as float)
{
    const int lane = threadIdx.x & 63;
    const int wid  = blockIdx.x * 4 + (threadIdx.x >> 6);  // 0 .. B*T-1
    const int b    = wid >> 12;        // / TT
    const int t    = wid & (TT - 1);   // % TT

    const int dl = lane * 4;           // this lane's base d within each 1KB round

    float dot[NN];
#pragma unroll
    for (int n = 0; n < NN; ++n) dot[n] = 0.0f;

#pragma unroll
    for (int n = 0; n < NN; ++n) {
        const float* ep = e + (((size_t)b * NN + n) * TT + t) * DD + dl;
        const float* wp = w + (size_t)n * DD + dl;
#pragma unroll
        for (int r = 0; r < 4; ++r) {
            const float4 ef = *reinterpret_cast<const float4*>(ep + r * 256);
            const float4 wf = *reinterpret_cast<const float4*>(wp + r * 256);
            dot[n] += ef.x * wf.x + ef.y * wf.y + ef.z * wf.z + ef.w * wf.w;
        }
    }

    // Full butterfly: all 64 lanes end with identical complete sums.
#pragma unroll
    for (int off = 32; off > 0; off >>= 1) {
#pragma unroll
        for (int n = 0; n < NN; ++n)
            dot[n] += __shfl_xor(dot[n], off, 64);
    }

    // Redundant per-lane sigmoid + argmax (identical in every lane).
    float best = -1.0f;
    int   bi   = 0;
#pragma unroll
    for (int n = 0; n < NN; ++n) {
        const float sn = 1.0f / (1.0f + expf(-dot[n]));   // f32-quantized
        if (sn > best) { best = sn; bi = n; }              // first-max tie-break
    }

    // Tiny aux outputs.
    if (lane == 0) {
        smax[wid] = best;
        sind[wid] = (float)bi;
    }
    if (lane < NN) {
        one_hot[((size_t)b * NN + lane) * TT + t] = (lane == bi) ? 1.0f : 0.0f;
    }

    // Re-read winner row (L1/L2-hot) and write scaled output.
    const float* wr = e + (((size_t)b * NN + bi) * TT + t) * DD + dl;
    float*       op = e_out + ((size_t)b * TT + t) * DD + dl;
#pragma unroll
    for (int r = 0; r < 4; ++r) {
        float4 o = *reinterpret_cast<const float4*>(wr + r * 256);
        o.x *= best; o.y *= best; o.z *= best; o.w *= best;
        *reinterpret_cast<float4*>(op + r * 256) = o;
    }
}

extern "C" void kernel_launch(void* const* d_in, const int* in_sizes, int n_in,
                              void* d_out, int out_size, void* d_ws, size_t ws_size,
                              hipStream_t stream) {
    const float* e = (const float*)d_in[0];   // [B,N,T,D] fp32
    const float* w = (const float*)d_in[1];   // [N,D,1]  fp32

    float* out     = (float*)d_out;
    float* e_out   = out;                                          // B*T*D
    float* one_hot = e_out + (size_t)BB * TT * DD;                 // B*N*T
    float* smax    = one_hot + (size_t)BB * NN * TT;               // B*T
    float* sind    = smax + (size_t)BB * TT;                       // B*T

    // 4 independent waves per block, one wave per (b,t).
    gate_kernel<<<(BB * TT) / 4, 256, 0, stream>>>(e, w, e_out, one_hot, smax, sind);
}

// Round 5
// 103.698 us; speedup vs baseline: 1.2165x; 1.1819x over previous
//
#include <hip/hip_runtime.h>
#include <math.h>

// Problem constants (from reference): B=4, N=8, T=4096, D=1024, TEMPERATURE=1
#define BB 4
#define NN 8
#define TT 4096
#define DD 1024

// Native clang vector type — required by __builtin_nontemporal_load/store
// (HIP_vector_type float4 is a class and is rejected).
typedef float vfloat4 __attribute__((ext_vector_type(4)));

// Wave-autonomous, online-argmax, zero re-read:
//   one 64-lane wave per (b,t); per concept n: read the 4KB row (16 floats/lane,
//   nontemporal — each line is consumed exactly once chip-wide), dot with w
//   (L1-hot), xor-butterfly (all lanes end with the bitwise-identical full dot),
//   f32-quantized sigmoid, and a wave-uniform select of the row fragments into
//   the running best row. At the end: scale best row by best sigmoid, NT-store.
//
// Correctness-critical (validated rounds 2-3): argmax over the f32-QUANTIZED
// sigmoid with strict > (first-index tie-break) — sigmoid saturates to exactly
// 1.0f for dot >~ 16.7, common here since dot ~ N(0,32); jnp.argmax takes the
// FIRST tied concept. Per-concept reduction order identical to round 3.
__global__ __launch_bounds__(256) void gate_kernel(
    const float* __restrict__ e,       // [B,N,T,D]
    const float* __restrict__ w,       // [N,D]
    float* __restrict__ e_out,         // [B,T,D]
    float* __restrict__ one_hot,       // [B,N,T] (0.0/1.0)
    float* __restrict__ smax,          // [B,T]
    float* __restrict__ sind)          // [B,T] (0..7 as float)
{
    const int lane = threadIdx.x & 63;
    const int wid  = blockIdx.x * 4 + (threadIdx.x >> 6);  // 0 .. B*T-1
    const int b    = wid >> 12;        // / TT
    const int t    = wid & (TT - 1);   // % TT
    const int dl   = lane * 4;         // lane's base d within each 1KB round

    float   best_s = -1.0f;            // sigmoid in (0,1): n=0 always wins init
    int     bi     = 0;
    vfloat4 bf0, bf1, bf2, bf3;        // running best row (16 floats/lane)

#pragma unroll
    for (int n = 0; n < NN; ++n) {
        const float* ep = e + (((size_t)b * NN + n) * TT + t) * DD + dl;
        const float* wp = w + (size_t)n * DD + dl;

        const vfloat4 c0 = __builtin_nontemporal_load(reinterpret_cast<const vfloat4*>(ep));
        const vfloat4 c1 = __builtin_nontemporal_load(reinterpret_cast<const vfloat4*>(ep + 256));
        const vfloat4 c2 = __builtin_nontemporal_load(reinterpret_cast<const vfloat4*>(ep + 512));
        const vfloat4 c3 = __builtin_nontemporal_load(reinterpret_cast<const vfloat4*>(ep + 768));
        const vfloat4 w0 = *reinterpret_cast<const vfloat4*>(wp);
        const vfloat4 w1 = *reinterpret_cast<const vfloat4*>(wp + 256);
        const vfloat4 w2 = *reinterpret_cast<const vfloat4*>(wp + 512);
        const vfloat4 w3 = *reinterpret_cast<const vfloat4*>(wp + 768);

        float dot = c0.x * w0.x + c0.y * w0.y + c0.z * w0.z + c0.w * w0.w;
        dot      += c1.x * w1.x + c1.y * w1.y + c1.z * w1.z + c1.w * w1.w;
        dot      += c2.x * w2.x + c2.y * w2.y + c2.z * w2.z + c2.w * w2.w;
        dot      += c3.x * w3.x + c3.y * w3.y + c3.z * w3.z + c3.w * w3.w;

#pragma unroll
        for (int off = 32; off > 0; off >>= 1)
            dot += __shfl_xor(dot, off, 64);

        const float sn = 1.0f / (1.0f + expf(-dot));   // f32-quantized sigmoid

        if (n == 0) {
            best_s = sn; bi = 0;
            bf0 = c0; bf1 = c1; bf2 = c2; bf3 = c3;
        } else {
            const bool take = (sn > best_s);           // wave-uniform
            if (take) { best_s = sn; bi = n; }
            bf0 = take ? c0 : bf0;
            bf1 = take ? c1 : bf1;
            bf2 = take ? c2 : bf2;
            bf3 = take ? c3 : bf3;
        }
    }

    // Tiny aux outputs.
    if (lane == 0) {
        smax[wid] = best_s;
        sind[wid] = (float)bi;
    }
    if (lane < NN) {
        one_hot[((size_t)b * NN + lane) * TT + t] = (lane == bi) ? 1.0f : 0.0f;
    }

    // Scale best row and NT-store (no reuse downstream).
    float* op = e_out + ((size_t)b * TT + t) * DD + dl;
    bf0 *= best_s; bf1 *= best_s; bf2 *= best_s; bf3 *= best_s;
    __builtin_nontemporal_store(bf0, reinterpret_cast<vfloat4*>(op));
    __builtin_nontemporal_store(bf1, reinterpret_cast<vfloat4*>(op + 256));
    __builtin_nontemporal_store(bf2, reinterpret_cast<vfloat4*>(op + 512));
    __builtin_nontemporal_store(bf3, reinterpret_cast<vfloat4*>(op + 768));
}

extern "C" void kernel_launch(void* const* d_in, const int* in_sizes, int n_in,
                              void* d_out, int out_size, void* d_ws, size_t ws_size,
                              hipStream_t stream) {
    const float* e = (const float*)d_in[0];   // [B,N,T,D] fp32
    const float* w = (const float*)d_in[1];   // [N,D,1]  fp32

    float* out     = (float*)d_out;
    float* e_out   = out;                                          // B*T*D
    float* one_hot = e_out + (size_t)BB * TT * DD;                 // B*N*T
    float* smax    = one_hot + (size_t)BB * NN * TT;               // B*T
    float* sind    = smax + (size_t)BB * TT;                       // B*T

    // 4 independent waves per block, one wave per (b,t).
    gate_kernel<<<(BB * TT) / 4, 256, 0, stream>>>(e, w, e_out, one_hot, smax, sind);
}

// Round 6
// 100.272 us; speedup vs baseline: 1.2581x; 1.0342x over previous
//
#include <hip/hip_runtime.h>
#include <math.h>

// Problem constants (from reference): B=4, N=8, T=4096, D=1024, TEMPERATURE=1
#define BB 4
#define NN 8
#define TT 4096
#define DD 1024

// Native clang vector type — required by __builtin_nontemporal_load/store.
typedef float vfloat4 __attribute__((ext_vector_type(4)));

// Wave-autonomous, online-argmax, zero re-read, TWO tokens per wave:
//   one 64-lane wave handles (b,t0) and (b,t0+1). Per concept n: read both
//   4KB rows (NT — consumed exactly once chip-wide), shared w fragments
//   (L1-hot), two independent xor-butterflies (interleaved -> latency
//   hiding), f32-quantized sigmoid, wave-uniform select of row fragments
//   into each token's running best row. End: scale + NT-store both rows.
//
// Correctness-critical (validated rounds 2-5): argmax over the f32-QUANTIZED
// sigmoid with strict > (first-index tie-break); per-token FMA/reduction
// order is bit-identical to the round-5 kernel (absmax must stay 0.0078).
__global__ __launch_bounds__(256) void gate_kernel(
    const float* __restrict__ e,       // [B,N,T,D]
    const float* __restrict__ w,       // [N,D]
    float* __restrict__ e_out,         // [B,T,D]
    float* __restrict__ one_hot,       // [B,N,T] (0.0/1.0)
    float* __restrict__ smax,          // [B,T]
    float* __restrict__ sind)          // [B,T] (0..7 as float)
{
    const int lane  = threadIdx.x & 63;
    const int wpair = blockIdx.x * 4 + (threadIdx.x >> 6);  // 0 .. B*T/2-1
    const int wid0  = wpair * 2;       // first token id (even)
    const int b     = wid0 >> 12;      // / TT  (same b for both tokens: T even)
    const int t0    = wid0 & (TT - 1); // even
    const int dl    = lane * 4;        // lane's base d within each 1KB round

    float   bsA = -1.0f, bsB = -1.0f;  // best sigmoid per token
    int     biA = 0,     biB = 0;
    vfloat4 a0, a1, a2, a3;            // running best row, token A (t0)
    vfloat4 e0, e1, e2, e3;            // running best row, token B (t0+1)

#pragma unroll
    for (int n = 0; n < NN; ++n) {
        const float* epA = e + (((size_t)b * NN + n) * TT + t0) * DD + dl;
        const float* epB = epA + DD;   // t0+1: adjacent 4KB row
        const float* wp  = w + (size_t)n * DD + dl;

        const vfloat4 cA0 = __builtin_nontemporal_load(reinterpret_cast<const vfloat4*>(epA));
        const vfloat4 cA1 = __builtin_nontemporal_load(reinterpret_cast<const vfloat4*>(epA + 256));
        const vfloat4 cA2 = __builtin_nontemporal_load(reinterpret_cast<const vfloat4*>(epA + 512));
        const vfloat4 cA3 = __builtin_nontemporal_load(reinterpret_cast<const vfloat4*>(epA + 768));
        const vfloat4 cB0 = __builtin_nontemporal_load(reinterpret_cast<const vfloat4*>(epB));
        const vfloat4 cB1 = __builtin_nontemporal_load(reinterpret_cast<const vfloat4*>(epB + 256));
        const vfloat4 cB2 = __builtin_nontemporal_load(reinterpret_cast<const vfloat4*>(epB + 512));
        const vfloat4 cB3 = __builtin_nontemporal_load(reinterpret_cast<const vfloat4*>(epB + 768));
        const vfloat4 w0  = *reinterpret_cast<const vfloat4*>(wp);
        const vfloat4 w1  = *reinterpret_cast<const vfloat4*>(wp + 256);
        const vfloat4 w2  = *reinterpret_cast<const vfloat4*>(wp + 512);
        const vfloat4 w3  = *reinterpret_cast<const vfloat4*>(wp + 768);

        // Per-token dot, FMA order identical to round-5 kernel.
        float dA = cA0.x * w0.x + cA0.y * w0.y + cA0.z * w0.z + cA0.w * w0.w;
        dA      += cA1.x * w1.x + cA1.y * w1.y + cA1.z * w1.z + cA1.w * w1.w;
        dA      += cA2.x * w2.x + cA2.y * w2.y + cA2.z * w2.z + cA2.w * w2.w;
        dA      += cA3.x * w3.x + cA3.y * w3.y + cA3.z * w3.z + cA3.w * w3.w;
        float dB = cB0.x * w0.x + cB0.y * w0.y + cB0.z * w0.z + cB0.w * w0.w;
        dB      += cB1.x * w1.x + cB1.y * w1.y + cB1.z * w1.z + cB1.w * w1.w;
        dB      += cB2.x * w2.x + cB2.y * w2.y + cB2.z * w2.z + cB2.w * w2.w;
        dB      += cB3.x * w3.x + cB3.y * w3.y + cB3.z * w3.z + cB3.w * w3.w;

        // Two independent butterflies, interleaved.
#pragma unroll
        for (int off = 32; off > 0; off >>= 1) {
            dA += __shfl_xor(dA, off, 64);
            dB += __shfl_xor(dB, off, 64);
        }

        const float sA = 1.0f / (1.0f + expf(-dA));   // f32-quantized sigmoid
        const float sB = 1.0f / (1.0f + expf(-dB));

        if (n == 0) {
            bsA = sA; biA = 0; a0 = cA0; a1 = cA1; a2 = cA2; a3 = cA3;
            bsB = sB; biB = 0; e0 = cB0; e1 = cB1; e2 = cB2; e3 = cB3;
        } else {
            const bool tkA = (sA > bsA);              // wave-uniform
            if (tkA) { bsA = sA; biA = n; }
            a0 = tkA ? cA0 : a0;  a1 = tkA ? cA1 : a1;
            a2 = tkA ? cA2 : a2;  a3 = tkA ? cA3 : a3;
            const bool tkB = (sB > bsB);
            if (tkB) { bsB = sB; biB = n; }
            e0 = tkB ? cB0 : e0;  e1 = tkB ? cB1 : e1;
            e2 = tkB ? cB2 : e2;  e3 = tkB ? cB3 : e3;
        }
    }

    // Tiny aux outputs (both tokens).
    if (lane == 0) {
        smax[wid0]     = bsA;  sind[wid0]     = (float)biA;
        smax[wid0 + 1] = bsB;  sind[wid0 + 1] = (float)biB;
    }
    if (lane < NN) {
        const size_t oh = ((size_t)b * NN + lane) * TT + t0;
        one_hot[oh]     = (lane == biA) ? 1.0f : 0.0f;
        one_hot[oh + 1] = (lane == biB) ? 1.0f : 0.0f;
    }

    // Scale best rows and NT-store (no reuse downstream).
    float* opA = e_out + ((size_t)b * TT + t0) * DD + dl;
    float* opB = opA + DD;
    a0 *= bsA; a1 *= bsA; a2 *= bsA; a3 *= bsA;
    e0 *= bsB; e1 *= bsB; e2 *= bsB; e3 *= bsB;
    __builtin_nontemporal_store(a0, reinterpret_cast<vfloat4*>(opA));
    __builtin_nontemporal_store(a1, reinterpret_cast<vfloat4*>(opA + 256));
    __builtin_nontemporal_store(a2, reinterpret_cast<vfloat4*>(opA + 512));
    __builtin_nontemporal_store(a3, reinterpret_cast<vfloat4*>(opA + 768));
    __builtin_nontemporal_store(e0, reinterpret_cast<vfloat4*>(opB));
    __builtin_nontemporal_store(e1, reinterpret_cast<vfloat4*>(opB + 256));
    __builtin_nontemporal_store(e2, reinterpret_cast<vfloat4*>(opB + 512));
    __builtin_nontemporal_store(e3, reinterpret_cast<vfloat4*>(opB + 768));
}

extern "C" void kernel_launch(void* const* d_in, const int* in_sizes, int n_in,
                              void* d_out, int out_size, void* d_ws, size_t ws_size,
                              hipStream_t stream) {
    const float* e = (const float*)d_in[0];   // [B,N,T,D] fp32
    const float* w = (const float*)d_in[1];   // [N,D,1]  fp32

    float* out     = (float*)d_out;
    float* e_out   = out;                                          // B*T*D
    float* one_hot = e_out + (size_t)BB * TT * DD;                 // B*N*T
    float* smax    = one_hot + (size_t)BB * NN * TT;               // B*T
    float* sind    = smax + (size_t)BB * TT;                       // B*T

    // 4 waves per block, each wave handles 2 adjacent tokens: B*T/2 waves.
    gate_kernel<<<(BB * TT) / 8, 256, 0, stream>>>(e, w, e_out, one_hot, smax, sind);
}